// Round 1
// baseline (205.459 us; speedup 1.0000x reference)
//
#include <hip/hip_runtime.h>

// Capsule dynamic routing — b-on-lanes / o-on-waves, wave-uniform weights.
// u_i:(B,N,DI) f32, w:(1,N,NO,DI,DE) f32, bias:(N,NO,1) f32, r=3.
// Identity: logits_r = u_ji . vsum (vsum = running sum of v; u_ji includes
// bias so the bias term folds in).
// routing block = 5 waves x 64 lanes; wave wv owns o in {2wv,2wv+1}; lane = b.
// Weight/bias addresses are wave-uniform (readfirstlane) -> scalar-load path.
// R7 changes vs R6:
//   (1) u is pre-transposed ONCE into ws as ut[n][half][b][4] so the per-n
//       u load is two fully-coalesced dwordx4 (64 lanes x 16B = 1KB) instead
//       of a 64-line gather replicated across 5 waves. Fallback to direct-u
//       path if ws_size too small.
//   (2) logit-exchange LDS is double-buffered (lgx[2][NO][BG], 5KB) -> one
//       __syncthreads per n instead of two (barrier i+1 separates iter-i
//       reads of buffer p from iter-i+2 writes of buffer p).

#define B    256
#define N    1152
#define NO   10
#define DI   8
#define DE   16
#define NTILE   8
#define NTILES  144    // N / NTILE
#define BG      64     // b per block (= lanes per wave)
#define BGS     4      // B / BG
#define THREADS 320    // 5 waves

// ws layout (floats)
#define SP_OFF 0
#define SP_SZ  (NTILES * B * NO * DE)   // 5,898,240
#define VS_OFF (SP_OFF + SP_SZ)
#define VS_SZ  (B * NO * DE)            // 40,960
#define UT_OFF (VS_OFF + VS_SZ)
#define UT_SZ  (2 * N * B * 4)          // 2,359,296 (= B*N*DI)

// ---------------------------------------------------------------------------
// One-time transpose: u (B,N,8) -> ut[((n*2+h)*B + b)*4 + j] = u[b][n][h*4+j]
// Reads are the (one-time) gather; writes are fully coalesced (1KB/wave/instr).
// Grid: (N/4, B/64) x 256 threads.
// ---------------------------------------------------------------------------
__global__ __launch_bounds__(256)
void transpose_kernel(const float* __restrict__ u, float* __restrict__ ut) {
    const int lane = threadIdx.x & 63;
    const int wv   = threadIdx.x >> 6;           // 0..3 -> n offset
    const int n    = blockIdx.x * 4 + wv;
    const int b    = blockIdx.y * 64 + lane;
    const float* up = u + ((size_t)b * N + n) * DI;
    const float4 a0 = *(const float4*)up;
    const float4 a1 = *(const float4*)(up + 4);
    *(float4*)(ut + ((size_t)(n * 2 + 0) * B + b) * 4) = a0;
    *(float4*)(ut + ((size_t)(n * 2 + 1) * B + b) * 4) = a1;
}

// ---------------------------------------------------------------------------
// Routing pass. Grid: (144 n-tiles, 4 b-groups) x 320 threads.
// ---------------------------------------------------------------------------
__global__ __launch_bounds__(THREADS, 3)
void routing_kernel(const float* __restrict__ u,
                    const float* __restrict__ ut,
                    const float* __restrict__ w,
                    const float* __restrict__ bias,
                    const float* __restrict__ vsum,
                    float* __restrict__ s_part,
                    const int has_v,
                    const int use_ut) {
    __shared__ float lgx[2][NO][BG];            // 5 KB double-buffered exchange
    const int tid  = threadIdx.x;
    const int lane = tid & 63;
    const int wv   = __builtin_amdgcn_readfirstlane(tid >> 6);  // 0..4, uniform
    const int o0   = wv * 2;
    const int b    = blockIdx.y * BG + lane;
    const int n0   = blockIdx.x * NTILE;

    // vsum fragment for this thread's (b, o0..o0+1), full e — loop-invariant
    float4 vv[2][4];
#pragma unroll
    for (int oi = 0; oi < 2; ++oi)
#pragma unroll
        for (int eq = 0; eq < 4; ++eq)
            vv[oi][eq] = make_float4(0.f, 0.f, 0.f, 0.f);
    if (has_v) {
#pragma unroll
        for (int oi = 0; oi < 2; ++oi)
#pragma unroll
            for (int eq = 0; eq < 4; ++eq)
                vv[oi][eq] = *(const float4*)(vsum + ((size_t)b * NO + o0 + oi) * DE + eq * 4);
    }

    float4 acc[2][4];
#pragma unroll
    for (int oi = 0; oi < 2; ++oi)
#pragma unroll
        for (int eq = 0; eq < 4; ++eq)
            acc[oi][eq] = make_float4(0.f, 0.f, 0.f, 0.f);

    for (int i = 0; i < NTILE; ++i) {
        const int n = n0 + i;

        // u row for lane's b — coalesced from ut (1KB/wave/instr), or legacy gather
        float4 u0, u1;
        if (use_ut) {
            const float* up = ut + ((size_t)(n * 2) * B + b) * 4;
            u0 = *(const float4*)up;
            u1 = *(const float4*)(up + B * 4);
        } else {
            const float* up = u + ((size_t)b * N + n) * DI;
            u0 = *(const float4*)up;
            u1 = *(const float4*)(up + 4);
        }
        const float ur[DI] = {u0.x, u0.y, u0.z, u0.w, u1.x, u1.y, u1.z, u1.w};

        // u_ji for (o0, o0+1), all 16 e — weight addrs wave-uniform
        const float* wp = w + ((size_t)n * NO + o0) * (DI * DE);
        float4 uji[2][4];
#pragma unroll
        for (int oi = 0; oi < 2; ++oi) {
            const float bv = bias[n * NO + o0 + oi];
#pragma unroll
            for (int eq = 0; eq < 4; ++eq)
                uji[oi][eq] = make_float4(bv, bv, bv, bv);
#pragma unroll
            for (int d = 0; d < DI; ++d) {
                const float* wrow = wp + oi * (DI * DE) + d * DE;
#pragma unroll
                for (int eq = 0; eq < 4; ++eq) {
                    const float4 w4 = *(const float4*)(wrow + eq * 4);
                    uji[oi][eq].x += ur[d] * w4.x;
                    uji[oi][eq].y += ur[d] * w4.y;
                    uji[oi][eq].z += ur[d] * w4.z;
                    uji[oi][eq].w += ur[d] * w4.w;
                }
            }
        }

        float c[2];
        if (has_v) {
            const int pb = i & 1;
            // logits: full-e dot in-thread, exchange via LDS for the softmax
#pragma unroll
            for (int oi = 0; oi < 2; ++oi) {
                float lg = 0.f;
#pragma unroll
                for (int eq = 0; eq < 4; ++eq)
                    lg += uji[oi][eq].x * vv[oi][eq].x + uji[oi][eq].y * vv[oi][eq].y
                        + uji[oi][eq].z * vv[oi][eq].z + uji[oi][eq].w * vv[oi][eq].w;
                lgx[pb][o0 + oi][lane] = lg;
            }
            __syncthreads();
            float l[NO];
#pragma unroll
            for (int o = 0; o < NO; ++o) l[o] = lgx[pb][o][lane];
            // no second barrier: buffer pb is next written at iter i+2, which
            // is separated from these reads by the barrier at iter i+1.

            float m = l[0];
#pragma unroll
            for (int o = 1; o < NO; ++o) m = fmaxf(m, l[o]);
            float sum = 0.f;
#pragma unroll
            for (int o = 0; o < NO; ++o) { l[o] = __expf(l[o] - m); sum += l[o]; }
            const float inv = 1.f / sum;
            c[0] = l[o0] * inv;
            c[1] = l[o0 + 1] * inv;
        } else {
            c[0] = 0.1f; c[1] = 0.1f;   // softmax of zeros
        }

#pragma unroll
        for (int oi = 0; oi < 2; ++oi)
#pragma unroll
            for (int eq = 0; eq < 4; ++eq) {
                acc[oi][eq].x += c[oi] * uji[oi][eq].x;
                acc[oi][eq].y += c[oi] * uji[oi][eq].y;
                acc[oi][eq].z += c[oi] * uji[oi][eq].z;
                acc[oi][eq].w += c[oi] * uji[oi][eq].w;
            }
    }

    // s_part[tile][b][o][e] — same layout squash already expects
    float* sp = s_part + (((size_t)blockIdx.x * B + b) * NO + o0) * DE;
#pragma unroll
    for (int oi = 0; oi < 2; ++oi)
#pragma unroll
        for (int eq = 0; eq < 4; ++eq)
            *(float4*)(sp + oi * DE + eq * 4) = acc[oi][eq];
}

// ---------------------------------------------------------------------------
// Squash (unchanged — proven): s = sum_tiles s_part;
// v = ||s||/(1+||s||^2)*s; out = v; vsum += v. 4 threads/element (36 tiles ea).
// t0: q = t0&3 (tile quarter), g = t0>>2 = (b*NO+o)*16 + e.
// ---------------------------------------------------------------------------
__global__ __launch_bounds__(256)
void squash_kernel(const float* __restrict__ s_part,
                   float* __restrict__ vsum,
                   float* __restrict__ out,
                   const int accum) {
    const int t0 = blockIdx.x * 256 + threadIdx.x;   // < 4*40960
    const int q  = t0 & 3;
    const int g  = t0 >> 2;

    float s = 0.f;
    const float* sp = s_part + (size_t)(q * 36) * (B * NO * DE) + g;
#pragma unroll 9
    for (int i = 0; i < 36; ++i)
        s += sp[(size_t)i * (B * NO * DE)];
    s += __shfl_xor(s, 1);
    s += __shfl_xor(s, 2);        // full tile sum, all q lanes

    float nsq = s * s;
#pragma unroll
    for (int msk = 4; msk <= 32; msk <<= 1) nsq += __shfl_xor(nsq, msk);
    const float nrm   = sqrtf(nsq);
    const float scale = nrm / (1.f + nsq);
    const float val   = s * scale;

    if (q == 0) {
        out[g]  = val;                               // (B,NO,DE)
        vsum[g] = accum ? (vsum[g] + val) : val;
    }
}

extern "C" void kernel_launch(void* const* d_in, const int* in_sizes, int n_in,
                              void* d_out, int out_size, void* d_ws, size_t ws_size,
                              hipStream_t stream) {
    const float* u    = (const float*)d_in[0];
    const float* w    = (const float*)d_in[1];   // (N,NO,DI,DE)
    const float* bias = (const float*)d_in[2];   // (N,NO)
    // d_in[3] = r, static 3

    float* wsf    = (float*)d_ws;
    float* s_part = wsf + SP_OFF;
    float* vsum   = wsf + VS_OFF;
    float* ut     = wsf + UT_OFF;
    float* out    = (float*)d_out;

    const int use_ut = (ws_size >= (size_t)(SP_SZ + VS_SZ + UT_SZ) * sizeof(float));

    if (use_ut)
        transpose_kernel<<<dim3(N / 4, B / 64), 256, 0, stream>>>(u, ut);

    for (int it = 0; it < 3; ++it) {
        routing_kernel<<<dim3(NTILES, BGS), THREADS, 0, stream>>>(
            u, ut, w, bias, vsum, s_part, it > 0, use_ut);
        squash_kernel<<<(4 * B * NO * DE) / 256, 256, 0, stream>>>(
            s_part, vsum, out, it > 0);
    }
}

// Round 2
// 194.436 us; speedup vs baseline: 1.0567x; 1.0567x over previous
//
#include <hip/hip_runtime.h>

// Capsule dynamic routing — b-on-lanes / o-on-waves, wave-uniform weights.
// u_i:(B,N,DI) f32, w:(1,N,NO,DI,DE) f32, bias:(N,NO,1) f32, r=3.
// Identity: logits_r = u_ji . vsum (vsum = running sum of v; u_ji includes
// bias so the bias term folds in).
// R8: routing block = 10 waves x 64 lanes; wave wv owns o = wv; lane = b.
//   R1 falsified the gather/barrier theory (it=0 launch == it>0 duration);
//   counters showed VALUBusy 20% / Occupancy 13.5% -> latency-bound.
//   1 o per thread halves per-thread state (~56 VGPR) and doubles resident
//   waves (22.5/CU vs 11) at identical memory traffic.
// Weight/bias addresses are wave-uniform (readfirstlane) -> scalar-load path.

#define B    256
#define N    1152
#define NO   10
#define DI   8
#define DE   16
#define NTILE   8
#define NTILES  144    // N / NTILE
#define BG      64     // b per block (= lanes per wave)
#define BGS     4      // B / BG
#define THREADS 640    // 10 waves, o = wave id

// ws layout (floats)
#define SP_OFF 0
#define SP_SZ  (NTILES * B * NO * DE)   // 5,898,240
#define VS_OFF (SP_OFF + SP_SZ)
#define VS_SZ  (B * NO * DE)            // 40,960
#define UT_OFF (VS_OFF + VS_SZ)
#define UT_SZ  (2 * N * B * 4)          // 2,359,296 (= B*N*DI)

// ---------------------------------------------------------------------------
// One-time transpose: u (B,N,8) -> ut[((n*2+h)*B + b)*4 + j] = u[b][n][h*4+j]
// ---------------------------------------------------------------------------
__global__ __launch_bounds__(256)
void transpose_kernel(const float* __restrict__ u, float* __restrict__ ut) {
    const int lane = threadIdx.x & 63;
    const int wv   = threadIdx.x >> 6;           // 0..3 -> n offset
    const int n    = blockIdx.x * 4 + wv;
    const int b    = blockIdx.y * 64 + lane;
    const float* up = u + ((size_t)b * N + n) * DI;
    const float4 a0 = *(const float4*)up;
    const float4 a1 = *(const float4*)(up + 4);
    *(float4*)(ut + ((size_t)(n * 2 + 0) * B + b) * 4) = a0;
    *(float4*)(ut + ((size_t)(n * 2 + 1) * B + b) * 4) = a1;
}

// ---------------------------------------------------------------------------
// Routing pass. Grid: (144 n-tiles, 4 b-groups) x 640 threads (10 waves).
// ---------------------------------------------------------------------------
__global__ __launch_bounds__(THREADS, 4)
void routing_kernel(const float* __restrict__ u,
                    const float* __restrict__ ut,
                    const float* __restrict__ w,
                    const float* __restrict__ bias,
                    const float* __restrict__ vsum,
                    float* __restrict__ s_part,
                    const int has_v,
                    const int use_ut) {
    __shared__ float lgx[2][NO][BG];            // 5 KB double-buffered exchange
    const int tid  = threadIdx.x;
    const int lane = tid & 63;
    const int wv   = __builtin_amdgcn_readfirstlane(tid >> 6);  // 0..9, uniform
    const int o    = wv;                         // one output capsule per wave
    const int b    = blockIdx.y * BG + lane;
    const int n0   = blockIdx.x * NTILE;

    // vsum fragment for this thread's (b, o), full e — loop-invariant
    float4 vv[4];
#pragma unroll
    for (int eq = 0; eq < 4; ++eq)
        vv[eq] = make_float4(0.f, 0.f, 0.f, 0.f);
    if (has_v) {
#pragma unroll
        for (int eq = 0; eq < 4; ++eq)
            vv[eq] = *(const float4*)(vsum + ((size_t)b * NO + o) * DE + eq * 4);
    }

    float4 acc[4];
#pragma unroll
    for (int eq = 0; eq < 4; ++eq)
        acc[eq] = make_float4(0.f, 0.f, 0.f, 0.f);

    for (int i = 0; i < NTILE; ++i) {
        const int n = n0 + i;

        // u row for lane's b — coalesced from ut (1KB/wave/instr), or legacy gather
        float4 u0, u1;
        if (use_ut) {
            const float* up = ut + ((size_t)(n * 2) * B + b) * 4;
            u0 = *(const float4*)up;
            u1 = *(const float4*)(up + B * 4);
        } else {
            const float* up = u + ((size_t)b * N + n) * DI;
            u0 = *(const float4*)up;
            u1 = *(const float4*)(up + 4);
        }
        const float ur[DI] = {u0.x, u0.y, u0.z, u0.w, u1.x, u1.y, u1.z, u1.w};

        // u_ji for this wave's o, all 16 e — weight addrs wave-uniform
        const float* wp = w + ((size_t)n * NO + o) * (DI * DE);
        const float bv = bias[n * NO + o];
        float4 uji[4];
#pragma unroll
        for (int eq = 0; eq < 4; ++eq)
            uji[eq] = make_float4(bv, bv, bv, bv);
#pragma unroll
        for (int d = 0; d < DI; ++d) {
            const float* wrow = wp + d * DE;
#pragma unroll
            for (int eq = 0; eq < 4; ++eq) {
                const float4 w4 = *(const float4*)(wrow + eq * 4);
                uji[eq].x += ur[d] * w4.x;
                uji[eq].y += ur[d] * w4.y;
                uji[eq].z += ur[d] * w4.z;
                uji[eq].w += ur[d] * w4.w;
            }
        }

        float c;
        if (has_v) {
            const int pb = i & 1;
            // logit: full-e dot in-thread, exchange via LDS for the softmax
            float lg = 0.f;
#pragma unroll
            for (int eq = 0; eq < 4; ++eq)
                lg += uji[eq].x * vv[eq].x + uji[eq].y * vv[eq].y
                    + uji[eq].z * vv[eq].z + uji[eq].w * vv[eq].w;
            lgx[pb][o][lane] = lg;
            __syncthreads();
            float l[NO];
#pragma unroll
            for (int oo = 0; oo < NO; ++oo) l[oo] = lgx[pb][oo][lane];
            // no second barrier: buffer pb is next written at iter i+2, which
            // is separated from these reads by the barrier at iter i+1.

            float m = l[0];
#pragma unroll
            for (int oo = 1; oo < NO; ++oo) m = fmaxf(m, l[oo]);
            float sum = 0.f;
#pragma unroll
            for (int oo = 0; oo < NO; ++oo) { l[oo] = __expf(l[oo] - m); sum += l[oo]; }
            c = l[o] / sum;
        } else {
            c = 0.1f;   // softmax of zeros
        }

#pragma unroll
        for (int eq = 0; eq < 4; ++eq) {
            acc[eq].x += c * uji[eq].x;
            acc[eq].y += c * uji[eq].y;
            acc[eq].z += c * uji[eq].z;
            acc[eq].w += c * uji[eq].w;
        }
    }

    // s_part[tile][b][o][e] — same layout squash already expects
    float* sp = s_part + (((size_t)blockIdx.x * B + b) * NO + o) * DE;
#pragma unroll
    for (int eq = 0; eq < 4; ++eq)
        *(float4*)(sp + eq * 4) = acc[eq];
}

// ---------------------------------------------------------------------------
// Squash (unchanged — proven): s = sum_tiles s_part;
// v = ||s||/(1+||s||^2)*s; out = v; vsum += v. 4 threads/element (36 tiles ea).
// ---------------------------------------------------------------------------
__global__ __launch_bounds__(256)
void squash_kernel(const float* __restrict__ s_part,
                   float* __restrict__ vsum,
                   float* __restrict__ out,
                   const int accum) {
    const int t0 = blockIdx.x * 256 + threadIdx.x;   // < 4*40960
    const int q  = t0 & 3;
    const int g  = t0 >> 2;

    float s = 0.f;
    const float* sp = s_part + (size_t)(q * 36) * (B * NO * DE) + g;
#pragma unroll 9
    for (int i = 0; i < 36; ++i)
        s += sp[(size_t)i * (B * NO * DE)];
    s += __shfl_xor(s, 1);
    s += __shfl_xor(s, 2);        // full tile sum, all q lanes

    float nsq = s * s;
#pragma unroll
    for (int msk = 4; msk <= 32; msk <<= 1) nsq += __shfl_xor(nsq, msk);
    const float nrm   = sqrtf(nsq);
    const float scale = nrm / (1.f + nsq);
    const float val   = s * scale;

    if (q == 0) {
        out[g]  = val;                               // (B,NO,DE)
        vsum[g] = accum ? (vsum[g] + val) : val;
    }
}

extern "C" void kernel_launch(void* const* d_in, const int* in_sizes, int n_in,
                              void* d_out, int out_size, void* d_ws, size_t ws_size,
                              hipStream_t stream) {
    const float* u    = (const float*)d_in[0];
    const float* w    = (const float*)d_in[1];   // (N,NO,DI,DE)
    const float* bias = (const float*)d_in[2];   // (N,NO)
    // d_in[3] = r, static 3

    float* wsf    = (float*)d_ws;
    float* s_part = wsf + SP_OFF;
    float* vsum   = wsf + VS_OFF;
    float* ut     = wsf + UT_OFF;
    float* out    = (float*)d_out;

    const int use_ut = (ws_size >= (size_t)(SP_SZ + VS_SZ + UT_SZ) * sizeof(float));

    if (use_ut)
        transpose_kernel<<<dim3(N / 4, B / 64), 256, 0, stream>>>(u, ut);

    for (int it = 0; it < 3; ++it) {
        routing_kernel<<<dim3(NTILES, BGS), THREADS, 0, stream>>>(
            u, ut, w, bias, vsum, s_part, it > 0, use_ut);
        squash_kernel<<<(4 * B * NO * DE) / 256, 256, 0, stream>>>(
            s_part, vsum, out, it > 0);
    }
}